// Round 1
// baseline (12654.382 us; speedup 1.0000x reference)
//
#include <hip/hip_runtime.h>
#include <cstddef>

#define TT 16384
#define NB 8
#define RES 120
#define SKIPC 240
#define NQ 256
#define TS 32
#define LSTR 36
#define HTS 16
#define HLSTR 20

__device__ __forceinline__ float4 mk4(float a, float b, float c, float d) {
  float4 v; v.x = a; v.y = b; v.z = c; v.w = d; return v;
}

// Pack Wf/Wg taps: wp[(i*RES+c)*RES+ci] = {Wf[..,0], Wf[..,1], Wg[..,0], Wg[..,1]}
__global__ void k_repack(const float* __restrict__ Wf, const float* __restrict__ Wg,
                         float4* __restrict__ wp) {
  int idx = blockIdx.x * blockDim.x + threadIdx.x;
  if (idx >= 16 * RES * RES) return;
  int b2 = idx * 2;
  wp[idx] = mk4(Wf[b2], Wf[b2 + 1], Wg[b2], Wg[b2 + 1]);
}

// x[b][c][t] = W_in[c] * wave[b][t] + b_in[c]
__global__ void k_input(const float* __restrict__ wave, const float* __restrict__ win,
                        const float* __restrict__ bin, float* __restrict__ x) {
  const int total = NB * RES * (TT / 4);
  for (int idx = blockIdx.x * blockDim.x + threadIdx.x; idx < total;
       idx += gridDim.x * blockDim.x) {
    int tq = idx % (TT / 4);
    int c = (idx / (TT / 4)) % RES;
    int b = idx / (RES * (TT / 4));
    float4 v = *(const float4*)(wave + (size_t)b * TT + tq * 4);
    float w = win[c], bi = bin[c];
    *(float4*)(x + ((size_t)b * RES + c) * TT + tq * 4) =
        mk4(w * v.x + bi, w * v.y + bi, w * v.z + bi, w * v.w + bi);
  }
}

// One residual block: f/g dilated K=2 convs -> z=tanh*sigmoid -> skip accum + res update
__global__ __launch_bounds__(256) void k_resblock(
    const float* __restrict__ xin, float* __restrict__ xout,
    float* __restrict__ skipbuf,           // out-layout: (b*NQ + c)*TT + t, c < SKIPC
    const float4* __restrict__ wfg,        // [RES][RES] packed taps for this block
    const float* __restrict__ bfp, const float* __restrict__ bgp,
    const float* __restrict__ wresp, const float* __restrict__ bresp,
    const float* __restrict__ wskipp, const float* __restrict__ bskipp,
    int dil, int first) {
  __shared__ float xc[RES][LSTR];
  __shared__ float xd[RES][LSTR];
  __shared__ float zs[RES][LSTR];

  const int b = blockIdx.y;
  const int t0 = blockIdx.x * TS;
  const float* xb = xin + (size_t)b * RES * TT;

  // stage current-tap tile (aligned float4)
  for (int idx = threadIdx.x; idx < RES * (TS / 4); idx += 256) {
    int c = idx >> 3, q = idx & 7;
    *(float4*)&xc[c][q * 4] = *(const float4*)(xb + (size_t)c * TT + t0 + q * 4);
  }
  // stage delayed-tap tile (scalar, zero-fill for t<0)
  for (int idx = threadIdx.x; idx < RES * TS; idx += 256) {
    int c = idx >> 5, t = idx & 31;
    int tg = t0 + t - dil;
    xd[c][t] = (tg >= 0) ? xb[(size_t)c * TT + tg] : 0.0f;
  }
  __syncthreads();

  const int cl = threadIdx.x & 63;
  const int th = threadIdx.x >> 6;  // 0..3
  const int tb = th * 8;
  const bool act = (cl < 60);
  const int c0 = cl * 2, c1 = c0 + 1;

  if (act) {
    float f0[8], f1[8], g0[8], g1[8];
    {
      float bf0 = bfp[c0], bf1 = bfp[c1], bg0 = bgp[c0], bg1 = bgp[c1];
#pragma unroll
      for (int q = 0; q < 8; q++) { f0[q] = bf0; f1[q] = bf1; g0[q] = bg0; g1[q] = bg1; }
    }
    for (int ci = 0; ci < RES; ci++) {
      float4 w0 = wfg[(size_t)c0 * RES + ci];
      float4 w1 = wfg[(size_t)c1 * RES + ci];
      float4 da = *(const float4*)&xd[ci][tb];
      float4 db = *(const float4*)&xd[ci][tb + 4];
      float4 ca = *(const float4*)&xc[ci][tb];
      float4 cb = *(const float4*)&xc[ci][tb + 4];
      float dv[8] = {da.x, da.y, da.z, da.w, db.x, db.y, db.z, db.w};
      float cv[8] = {ca.x, ca.y, ca.z, ca.w, cb.x, cb.y, cb.z, cb.w};
#pragma unroll
      for (int q = 0; q < 8; q++) {
        f0[q] += w0.x * dv[q] + w0.y * cv[q];
        g0[q] += w0.z * dv[q] + w0.w * cv[q];
        f1[q] += w1.x * dv[q] + w1.y * cv[q];
        g1[q] += w1.z * dv[q] + w1.w * cv[q];
      }
    }
    float z0[8], z1[8];
#pragma unroll
    for (int q = 0; q < 8; q++) {
      float tf = 1.0f - 2.0f / (__expf(2.0f * f0[q]) + 1.0f);
      float sg = 1.0f / (1.0f + __expf(-g0[q]));
      z0[q] = tf * sg;
      tf = 1.0f - 2.0f / (__expf(2.0f * f1[q]) + 1.0f);
      sg = 1.0f / (1.0f + __expf(-g1[q]));
      z1[q] = tf * sg;
    }
    *(float4*)&zs[c0][tb] = mk4(z0[0], z0[1], z0[2], z0[3]);
    *(float4*)&zs[c0][tb + 4] = mk4(z0[4], z0[5], z0[6], z0[7]);
    *(float4*)&zs[c1][tb] = mk4(z1[0], z1[1], z1[2], z1[3]);
    *(float4*)&zs[c1][tb + 4] = mk4(z1[4], z1[5], z1[6], z1[7]);
  }
  __syncthreads();

  // ---- skip contributions (two row-groups of 120) ----
#pragma unroll
  for (int p = 0; p < 2; p++) {
    if (act) {
      const int s0 = p * RES + c0;
      const int s1 = p * RES + c1;
      const float* wrow0 = wskipp + (size_t)s0 * RES;
      const float* wrow1 = wskipp + (size_t)s1 * RES;
      float a0[8], a1[8];
#pragma unroll
      for (int q = 0; q < 8; q++) { a0[q] = 0.f; a1[q] = 0.f; }
      for (int c4 = 0; c4 < RES / 4; c4++) {
        float4 w0q = *(const float4*)(wrow0 + c4 * 4);
        float4 w1q = *(const float4*)(wrow1 + c4 * 4);
#pragma unroll
        for (int j = 0; j < 4; j++) {
          const int ci = c4 * 4 + j;
          const float w0 = j == 0 ? w0q.x : j == 1 ? w0q.y : j == 2 ? w0q.z : w0q.w;
          const float w1 = j == 0 ? w1q.x : j == 1 ? w1q.y : j == 2 ? w1q.z : w1q.w;
          float4 za = *(const float4*)&zs[ci][tb];
          float4 zb = *(const float4*)&zs[ci][tb + 4];
          a0[0] += w0 * za.x; a0[1] += w0 * za.y; a0[2] += w0 * za.z; a0[3] += w0 * za.w;
          a0[4] += w0 * zb.x; a0[5] += w0 * zb.y; a0[6] += w0 * zb.z; a0[7] += w0 * zb.w;
          a1[0] += w1 * za.x; a1[1] += w1 * za.y; a1[2] += w1 * za.z; a1[3] += w1 * za.w;
          a1[4] += w1 * zb.x; a1[5] += w1 * zb.y; a1[6] += w1 * zb.z; a1[7] += w1 * zb.w;
        }
      }
      const float bs0 = bskipp[s0], bs1 = bskipp[s1];
      float* sp0 = skipbuf + ((size_t)b * NQ + s0) * TT + t0 + tb;
      float* sp1 = skipbuf + ((size_t)b * NQ + s1) * TT + t0 + tb;
      if (first) {
        *(float4*)sp0 = mk4(a0[0] + bs0, a0[1] + bs0, a0[2] + bs0, a0[3] + bs0);
        *(float4*)(sp0 + 4) = mk4(a0[4] + bs0, a0[5] + bs0, a0[6] + bs0, a0[7] + bs0);
        *(float4*)sp1 = mk4(a1[0] + bs1, a1[1] + bs1, a1[2] + bs1, a1[3] + bs1);
        *(float4*)(sp1 + 4) = mk4(a1[4] + bs1, a1[5] + bs1, a1[6] + bs1, a1[7] + bs1);
      } else {
        float4 o0 = *(const float4*)sp0, o1 = *(const float4*)(sp0 + 4);
        float4 o2 = *(const float4*)sp1, o3 = *(const float4*)(sp1 + 4);
        *(float4*)sp0 = mk4(o0.x + a0[0] + bs0, o0.y + a0[1] + bs0, o0.z + a0[2] + bs0, o0.w + a0[3] + bs0);
        *(float4*)(sp0 + 4) = mk4(o1.x + a0[4] + bs0, o1.y + a0[5] + bs0, o1.z + a0[6] + bs0, o1.w + a0[7] + bs0);
        *(float4*)sp1 = mk4(o2.x + a1[0] + bs1, o2.y + a1[1] + bs1, o2.z + a1[2] + bs1, o2.w + a1[3] + bs1);
        *(float4*)(sp1 + 4) = mk4(o3.x + a1[4] + bs1, o3.y + a1[5] + bs1, o3.z + a1[6] + bs1, o3.w + a1[7] + bs1);
      }
    }
  }

  // ---- residual update ----
  if (act) {
    const float* wrow0 = wresp + (size_t)c0 * RES;
    const float* wrow1 = wresp + (size_t)c1 * RES;
    float a0[8], a1[8];
#pragma unroll
    for (int q = 0; q < 8; q++) { a0[q] = 0.f; a1[q] = 0.f; }
    for (int c4 = 0; c4 < RES / 4; c4++) {
      float4 w0q = *(const float4*)(wrow0 + c4 * 4);
      float4 w1q = *(const float4*)(wrow1 + c4 * 4);
#pragma unroll
      for (int j = 0; j < 4; j++) {
        const int ci = c4 * 4 + j;
        const float w0 = j == 0 ? w0q.x : j == 1 ? w0q.y : j == 2 ? w0q.z : w0q.w;
        const float w1 = j == 0 ? w1q.x : j == 1 ? w1q.y : j == 2 ? w1q.z : w1q.w;
        float4 za = *(const float4*)&zs[ci][tb];
        float4 zb = *(const float4*)&zs[ci][tb + 4];
        a0[0] += w0 * za.x; a0[1] += w0 * za.y; a0[2] += w0 * za.z; a0[3] += w0 * za.w;
        a0[4] += w0 * zb.x; a0[5] += w0 * zb.y; a0[6] += w0 * zb.z; a0[7] += w0 * zb.w;
        a1[0] += w1 * za.x; a1[1] += w1 * za.y; a1[2] += w1 * za.z; a1[3] += w1 * za.w;
        a1[4] += w1 * zb.x; a1[5] += w1 * zb.y; a1[6] += w1 * zb.z; a1[7] += w1 * zb.w;
      }
    }
    const float br0 = bresp[c0], br1 = bresp[c1];
    float4 xa = *(const float4*)&xc[c0][tb];
    float4 xb4 = *(const float4*)&xc[c0][tb + 4];
    float4 ya = *(const float4*)&xc[c1][tb];
    float4 yb = *(const float4*)&xc[c1][tb + 4];
    float* xp0 = xout + ((size_t)b * RES + c0) * TT + t0 + tb;
    float* xp1 = xout + ((size_t)b * RES + c1) * TT + t0 + tb;
    *(float4*)xp0 = mk4(xa.x + a0[0] + br0, xa.y + a0[1] + br0, xa.z + a0[2] + br0, xa.w + a0[3] + br0);
    *(float4*)(xp0 + 4) = mk4(xb4.x + a0[4] + br0, xb4.y + a0[5] + br0, xb4.z + a0[6] + br0, xb4.w + a0[7] + br0);
    *(float4*)xp1 = mk4(ya.x + a1[0] + br1, ya.y + a1[1] + br1, ya.z + a1[2] + br1, ya.w + a1[3] + br1);
    *(float4*)(xp1 + 4) = mk4(yb.x + a1[4] + br1, yb.y + a1[5] + br1, yb.z + a1[6] + br1, yb.w + a1[7] + br1);
  }
}

// head: h = relu(skip); h1 = relu(W1 h + b1); out = W2 h1 + b2
__global__ __launch_bounds__(256) void k_head(
    const float* __restrict__ skipbuf, const float* __restrict__ w1,
    const float* __restrict__ b1, const float* __restrict__ w2,
    const float* __restrict__ b2, float* __restrict__ out) {
  __shared__ float hs[SKIPC][HLSTR];
  __shared__ float h1[NQ][HLSTR];
  const int b = blockIdx.y;
  const int t0 = blockIdx.x * HTS;
  const float* sb = skipbuf + (size_t)b * NQ * TT;  // out-layout rows

  for (int idx = threadIdx.x; idx < SKIPC * (HTS / 4); idx += 256) {
    int c = idx >> 2, q = idx & 3;
    float4 v = *(const float4*)(sb + (size_t)c * TT + t0 + q * 4);
    *(float4*)&hs[c][q * 4] = mk4(fmaxf(v.x, 0.f), fmaxf(v.y, 0.f),
                                  fmaxf(v.z, 0.f), fmaxf(v.w, 0.f));
  }
  __syncthreads();

  const int c = threadIdx.x;  // 0..255
  float acc[HTS];
#pragma unroll
  for (int q = 0; q < HTS; q++) acc[q] = b1[c];
  for (int c4 = 0; c4 < SKIPC / 4; c4++) {
    float4 wq = *(const float4*)(w1 + (size_t)c * SKIPC + c4 * 4);
#pragma unroll
    for (int j = 0; j < 4; j++) {
      const int ci = c4 * 4 + j;
      const float w = j == 0 ? wq.x : j == 1 ? wq.y : j == 2 ? wq.z : wq.w;
#pragma unroll
      for (int qq = 0; qq < 4; qq++) {
        float4 hv = *(const float4*)&hs[ci][qq * 4];
        acc[qq * 4 + 0] += w * hv.x; acc[qq * 4 + 1] += w * hv.y;
        acc[qq * 4 + 2] += w * hv.z; acc[qq * 4 + 3] += w * hv.w;
      }
    }
  }
#pragma unroll
  for (int q = 0; q < 4; q++)
    *(float4*)&h1[c][q * 4] = mk4(fmaxf(acc[q * 4 + 0], 0.f), fmaxf(acc[q * 4 + 1], 0.f),
                                  fmaxf(acc[q * 4 + 2], 0.f), fmaxf(acc[q * 4 + 3], 0.f));
  __syncthreads();

#pragma unroll
  for (int q = 0; q < HTS; q++) acc[q] = b2[c];
  for (int c4 = 0; c4 < NQ / 4; c4++) {
    float4 wq = *(const float4*)(w2 + (size_t)c * NQ + c4 * 4);
#pragma unroll
    for (int j = 0; j < 4; j++) {
      const int ci = c4 * 4 + j;
      const float w = j == 0 ? wq.x : j == 1 ? wq.y : j == 2 ? wq.z : wq.w;
#pragma unroll
      for (int qq = 0; qq < 4; qq++) {
        float4 hv = *(const float4*)&h1[ci][qq * 4];
        acc[qq * 4 + 0] += w * hv.x; acc[qq * 4 + 1] += w * hv.y;
        acc[qq * 4 + 2] += w * hv.z; acc[qq * 4 + 3] += w * hv.w;
      }
    }
  }
  float* op = out + ((size_t)b * NQ + c) * TT + t0;
#pragma unroll
  for (int q = 0; q < 4; q++)
    *(float4*)(op + q * 4) = mk4(acc[q * 4 + 0], acc[q * 4 + 1], acc[q * 4 + 2], acc[q * 4 + 3]);
}

extern "C" void kernel_launch(void* const* d_in, const int* in_sizes, int n_in,
                              void* d_out, int out_size, void* d_ws, size_t ws_size,
                              hipStream_t stream) {
  const float* wave  = (const float*)d_in[0];
  const float* W_in  = (const float*)d_in[1];
  const float* b_in  = (const float*)d_in[2];
  const float* Wf    = (const float*)d_in[3];
  const float* bfp   = (const float*)d_in[4];
  const float* Wg    = (const float*)d_in[5];
  const float* bgp   = (const float*)d_in[6];
  const float* Wres  = (const float*)d_in[7];
  const float* bres  = (const float*)d_in[8];
  const float* Wskip = (const float*)d_in[9];
  const float* bskip = (const float*)d_in[10];
  const float* W1    = (const float*)d_in[11];
  const float* b1    = (const float*)d_in[12];
  const float* W2    = (const float*)d_in[13];
  const float* b2    = (const float*)d_in[14];
  float* out = (float*)d_out;

  const size_t NX = (size_t)NB * RES * TT;  // 15,728,640 floats
  float* xA = (float*)d_ws;
  float* xB = xA + NX;
  float4* wp = (float4*)(xB + NX);
  float* skipbuf = out;  // skip_sum overlaid in d_out (row stride NQ*TT, c<240)

  k_repack<<<(16 * RES * RES + 255) / 256, 256, 0, stream>>>(Wf, Wg, wp);
  k_input<<<2048, 256, 0, stream>>>(wave, W_in, b_in, xA);

  static const int dils[16] = {1, 2, 4, 8, 16, 32, 64, 128,
                               1, 2, 4, 8, 16, 32, 64, 128};
  const float* xi = xA;
  float* xo = xB;
  for (int i = 0; i < 16; i++) {
    k_resblock<<<dim3(TT / TS, NB), 256, 0, stream>>>(
        xi, xo, skipbuf, wp + (size_t)i * RES * RES,
        bfp + i * RES, bgp + i * RES,
        Wres + (size_t)i * RES * RES, bres + i * RES,
        Wskip + (size_t)i * SKIPC * RES, bskip + i * SKIPC,
        dils[i], i == 0 ? 1 : 0);
    const float* t = xo; xo = (float*)xi; xi = t;
  }
  k_head<<<dim3(TT / HTS, NB), 256, 0, stream>>>(skipbuf, W1, b1, W2, b2, out);
}

// Round 2
// 4027.033 us; speedup vs baseline: 3.1424x; 3.1424x over previous
//
#include <hip/hip_runtime.h>
#include <cstddef>

#define TT 16384
#define NBATCH 8
#define CH 128        // padded residual channels
#define RES 120
#define SKIPC 240
#define NQ 256
#define NT 64         // timesteps per workgroup

typedef __attribute__((ext_vector_type(8))) short bf8;   // 8 bf16 (4 VGPR)
typedef __attribute__((ext_vector_type(4))) short s4;    // 4 bf16 (8B)
typedef __attribute__((ext_vector_type(4))) float f32x4;

__device__ __forceinline__ short f2bf(float f) {
  unsigned u = __builtin_bit_cast(unsigned, f);
  u += 0x7fffu + ((u >> 16) & 1u);
  return (short)(u >> 16);
}
__device__ __forceinline__ float bf2f(short s) {
  unsigned u = ((unsigned)(unsigned short)s) << 16;
  return __builtin_bit_cast(float, u);
}

// ---- pack all weights to bf16, padded, MFMA row-major [M][K] ----
// Afg[16][256][256]: rows 0-119 Wf (pad->127), 128-247 Wg; k<128 tap0(delayed), k>=128 tap1(current)
// Ars[16][384][128]: rows 0-119 Wres, 128-367 Wskip
// W1p[256][256] (K pad 240->256), W2p[256][256]
// biasp: [0,2048) bf | [2048,4096) bg | [4096,6144) bres | [6144,10240) bskip (per-layer 128/128/128/256)
__global__ void k_pack(const float* __restrict__ Wf, const float* __restrict__ Wg,
                       const float* __restrict__ Wres, const float* __restrict__ Wskip,
                       const float* __restrict__ W1, const float* __restrict__ W2,
                       const float* __restrict__ bf, const float* __restrict__ bg,
                       const float* __restrict__ bres, const float* __restrict__ bskip,
                       short* __restrict__ Afg, short* __restrict__ Ars,
                       short* __restrict__ W1p, short* __restrict__ W2p,
                       float* __restrict__ biasp) {
  const int NAFG = 16 * 256 * 256;   // 1048576
  const int NARS = 16 * 384 * 128;   // 786432
  const int NW = 256 * 256;          // 65536
  const int NBIA = 16 * (128 * 3 + 256);
  const int total = NAFG + NARS + 2 * NW + NBIA;
  for (int idx = blockIdx.x * blockDim.x + threadIdx.x; idx < total;
       idx += gridDim.x * blockDim.x) {
    if (idx < NAFG) {
      int i = idx >> 16, rem = idx & 65535, m = rem >> 8, k = rem & 255;
      int tap = k >> 7, ci = k & 127;
      float v = 0.f;
      if (ci < 120) {
        if (m < 120) v = Wf[((i * 120 + m) * 120 + ci) * 2 + tap];
        else if (m >= 128 && m < 248) v = Wg[((i * 120 + (m - 128)) * 120 + ci) * 2 + tap];
      }
      Afg[idx] = f2bf(v);
    } else if (idx < NAFG + NARS) {
      int j = idx - NAFG;
      int i = j / 49152, rem = j % 49152, m = rem >> 7, k = rem & 127;
      float v = 0.f;
      if (k < 120) {
        if (m < 120) v = Wres[(i * 120 + m) * 120 + k];
        else if (m >= 128 && m < 368) v = Wskip[(i * 240 + (m - 128)) * 120 + k];
      }
      Ars[j] = f2bf(v);
    } else if (idx < NAFG + NARS + NW) {
      int j = idx - NAFG - NARS, q = j >> 8, k = j & 255;
      W1p[j] = f2bf(k < 240 ? W1[q * 240 + k] : 0.f);
    } else if (idx < NAFG + NARS + 2 * NW) {
      int j = idx - NAFG - NARS - NW;
      W2p[j] = f2bf(W2[j]);
    } else {
      int j = idx - NAFG - NARS - 2 * NW;
      float v = 0.f;
      if (j < 2048) { int i = j >> 7, c = j & 127; if (c < 120) v = bf[i * 120 + c]; }
      else if (j < 4096) { int jj = j - 2048; int i = jj >> 7, c = jj & 127; if (c < 120) v = bg[i * 120 + c]; }
      else if (j < 6144) { int jj = j - 4096; int i = jj >> 7, c = jj & 127; if (c < 120) v = bres[i * 120 + c]; }
      else { int jj = j - 6144; int i = jj >> 8, c = jj & 255; if (c < 240) v = bskip[i * 240 + c]; }
      biasp[j] = v;
    }
  }
}

// x0[b][t][c] = bf16(W_in[c]*wave[b][t] + b_in[c]), pad channels zero
__global__ void k_input(const float* __restrict__ wave, const float* __restrict__ win,
                        const float* __restrict__ bin, short* __restrict__ x0) {
  int idx = blockIdx.x * blockDim.x + threadIdx.x;  // one per (b,t)
  if (idx >= NBATCH * TT) return;
  float wv = wave[idx];
  short* row = x0 + (size_t)idx * CH;
  for (int c = 0; c < CH; c += 4) {
    s4 v;
#pragma unroll
    for (int j = 0; j < 4; j++)
      v[j] = (c + j < 120) ? f2bf(win[c + j] * wv + bin[c + j]) : (short)0;
    *(s4*)(row + c) = v;
  }
}

// One residual block, MFMA. Grid (TT/NT, NBATCH), 256 threads (4 waves).
__global__ __launch_bounds__(256) void k_res_mfma(
    const short* __restrict__ xin, short* __restrict__ xout,
    float* __restrict__ skip,                 // d_out overlay [B][256][T], rows<240
    const short* __restrict__ Afg, const short* __restrict__ Ars,
    const float* __restrict__ biasp, int layer, int dil, int first) {
  __shared__ short zT[NT][136];
  const int b = blockIdx.y;
  const int t0 = blockIdx.x * NT;
  const int tid = threadIdx.x;
  const int lane = tid & 63, w = tid >> 6;
  const int l15 = lane & 15, l4 = lane >> 4;
  const size_t xbase = (size_t)b * TT * CH;

  // ---------------- Phase A: fg GEMM  M=256 K=256 N=64 ----------------
  f32x4 fa[2][4], ga[2][4];
#pragma unroll
  for (int i = 0; i < 2; i++)
#pragma unroll
    for (int j = 0; j < 4; j++) { fa[i][j] = (f32x4)0.f; ga[i][j] = (f32x4)0.f; }

  const short* pBd[4];
  const short* pBc[4];
  bool vld[4];
#pragma unroll
  for (int nt = 0; nt < 4; nt++) {
    int t = t0 + nt * 16 + l15;
    int ts = t - dil;
    vld[nt] = (ts >= 0);
    pBd[nt] = xin + xbase + (size_t)(vld[nt] ? ts : 0) * CH + l4 * 8;
    pBc[nt] = xin + xbase + (size_t)t * CH + l4 * 8;
  }
  const short* pAf[2];
  const short* pAg[2];
#pragma unroll
  for (int mt = 0; mt < 2; mt++) {
    pAf[mt] = Afg + (size_t)(w * 32 + mt * 16 + l15) * 256 + l4 * 8;
    pAg[mt] = Afg + (size_t)(128 + w * 32 + mt * 16 + l15) * 256 + l4 * 8;
  }
  const bf8 zv = (bf8)(short)0;
#pragma unroll
  for (int kk = 0; kk < 8; kk++) {
    const int k = kk * 32;  // k<128: delayed tap, k>=128: current tap
    bf8 Bv[4];
#pragma unroll
    for (int nt = 0; nt < 4; nt++) {
      if (kk < 4) {
        bf8 v = *(const bf8*)(pBd[nt] + k);
        Bv[nt] = vld[nt] ? v : zv;
      } else {
        Bv[nt] = *(const bf8*)(pBc[nt] + (k - 128));
      }
    }
#pragma unroll
    for (int mt = 0; mt < 2; mt++) {
      bf8 Av = *(const bf8*)(pAf[mt] + k);
      bf8 Gv = *(const bf8*)(pAg[mt] + k);
#pragma unroll
      for (int nt = 0; nt < 4; nt++) {
        fa[mt][nt] = __builtin_amdgcn_mfma_f32_16x16x32_bf16(Av, Bv[nt], fa[mt][nt], 0, 0, 0);
        ga[mt][nt] = __builtin_amdgcn_mfma_f32_16x16x32_bf16(Gv, Bv[nt], ga[mt][nt], 0, 0, 0);
      }
    }
  }

  // activation: z = tanh(f+bf)*sigmoid(g+bg), write transposed to LDS
  const float* bf_ = biasp + (size_t)layer * 128;
  const float* bg_ = biasp + 2048 + (size_t)layer * 128;
#pragma unroll
  for (int mt = 0; mt < 2; mt++) {
    int mb = w * 32 + mt * 16 + l4 * 4;
#pragma unroll
    for (int nt = 0; nt < 4; nt++) {
      s4 zp;
#pragma unroll
      for (int r = 0; r < 4; r++) {
        float f = fa[mt][nt][r] + bf_[mb + r];
        float g = ga[mt][nt][r] + bg_[mb + r];
        float th = 1.f - 2.f / (__expf(2.f * f) + 1.f);
        float sg = 1.f / (1.f + __expf(-g));
        zp[r] = f2bf(th * sg);
      }
      *(s4*)&zT[nt * 16 + l15][mb] = zp;
    }
  }
  __syncthreads();

  // ---------------- Phase B: res+skip GEMM  M=384 K=128 N=64 ----------------
  f32x4 acc[6][4];
#pragma unroll
  for (int i = 0; i < 6; i++)
#pragma unroll
    for (int j = 0; j < 4; j++) acc[i][j] = (f32x4)0.f;
  const short* pA[6];
#pragma unroll
  for (int mt = 0; mt < 6; mt++)
    pA[mt] = Ars + (size_t)(w * 96 + mt * 16 + l15) * 128 + l4 * 8;
#pragma unroll
  for (int kk = 0; kk < 4; kk++) {
    const int k = kk * 32;
    bf8 Bv[4];
#pragma unroll
    for (int nt = 0; nt < 4; nt++) Bv[nt] = *(const bf8*)&zT[nt * 16 + l15][k + l4 * 8];
#pragma unroll
    for (int mt = 0; mt < 6; mt++) {
      bf8 Av = *(const bf8*)(pA[mt] + k);
#pragma unroll
      for (int nt = 0; nt < 4; nt++)
        acc[mt][nt] = __builtin_amdgcn_mfma_f32_16x16x32_bf16(Av, Bv[nt], acc[mt][nt], 0, 0, 0);
    }
  }

  const float* br_ = biasp + 4096 + (size_t)layer * 128;
  const float* bs_ = biasp + 6144 + (size_t)layer * 256;
#pragma unroll
  for (int mt = 0; mt < 6; mt++) {
    int m = w * 96 + mt * 16 + l4 * 4;
#pragma unroll
    for (int nt = 0; nt < 4; nt++) {
      int t = t0 + nt * 16 + l15;
      if (m < 128) {
        // residual: xout = xin + r + bres  (pad rows stay zero automatically)
        s4 xv = *(const s4*)(xin + xbase + (size_t)t * CH + m);
        s4 ov;
#pragma unroll
        for (int r = 0; r < 4; r++)
          ov[r] = f2bf(bf2f(xv[r]) + acc[mt][nt][r] + br_[m + r]);
        *(s4*)(xout + xbase + (size_t)t * CH + m) = ov;
      } else if (m < 128 + SKIPC) {
        int c = m - 128;
        float* sp = skip + ((size_t)b * NQ + c) * TT + t;
#pragma unroll
        for (int r = 0; r < 4; r++) {
          float v = acc[mt][nt][r] + bs_[c + r];
          if (!first) v += sp[(size_t)r * TT];
          sp[(size_t)r * TT] = v;
        }
      }
    }
  }
}

// head: relu(skip) -> W1 relu -> W2, all MFMA. skip/out share d_out (same t-columns).
__global__ __launch_bounds__(256) void k_head_mfma(
    const float* skip, const short* __restrict__ W1p, const float* __restrict__ b1,
    const short* __restrict__ W2p, const float* __restrict__ b2, float* out) {
  __shared__ short hT[NT][264];
  __shared__ short h2T[NT][264];
  const int b = blockIdx.y;
  const int t0 = blockIdx.x * NT;
  const int tid = threadIdx.x;
  const int lane = tid & 63, w = tid >> 6;
  const int l15 = lane & 15, l4 = lane >> 4;

  // stage relu(skip) transposed into LDS, K pad 240->256 with zeros
  for (int u = tid; u < 256 * 16; u += 256) {
    int c = u >> 4, tq = u & 15;
    if (c < SKIPC) {
      f32x4 v = *(const f32x4*)(skip + ((size_t)b * NQ + c) * TT + t0 + tq * 4);
#pragma unroll
      for (int j = 0; j < 4; j++) hT[tq * 4 + j][c] = f2bf(fmaxf(v[j], 0.f));
    } else {
#pragma unroll
      for (int j = 0; j < 4; j++) hT[tq * 4 + j][c] = 0;
    }
  }
  __syncthreads();

  // GEMM1: M=256 K=256 N=64
  f32x4 acc[4][4];
#pragma unroll
  for (int i = 0; i < 4; i++)
#pragma unroll
    for (int j = 0; j < 4; j++) acc[i][j] = (f32x4)0.f;
#pragma unroll
  for (int kk = 0; kk < 8; kk++) {
    const int k = kk * 32;
    bf8 Bv[4];
#pragma unroll
    for (int nt = 0; nt < 4; nt++) Bv[nt] = *(const bf8*)&hT[nt * 16 + l15][k + l4 * 8];
#pragma unroll
    for (int mt = 0; mt < 4; mt++) {
      bf8 Av = *(const bf8*)(W1p + (size_t)(w * 64 + mt * 16 + l15) * 256 + k + l4 * 8);
#pragma unroll
      for (int nt = 0; nt < 4; nt++)
        acc[mt][nt] = __builtin_amdgcn_mfma_f32_16x16x32_bf16(Av, Bv[nt], acc[mt][nt], 0, 0, 0);
    }
  }
  // h1 = relu(acc + b1) -> h2T
#pragma unroll
  for (int mt = 0; mt < 4; mt++) {
    int mb = w * 64 + mt * 16 + l4 * 4;
#pragma unroll
    for (int nt = 0; nt < 4; nt++) {
      s4 hp;
#pragma unroll
      for (int r = 0; r < 4; r++) hp[r] = f2bf(fmaxf(acc[mt][nt][r] + b1[mb + r], 0.f));
      *(s4*)&h2T[nt * 16 + l15][mb] = hp;
    }
  }
  __syncthreads();

  // GEMM2: M=256 K=256 N=64
#pragma unroll
  for (int i = 0; i < 4; i++)
#pragma unroll
    for (int j = 0; j < 4; j++) acc[i][j] = (f32x4)0.f;
#pragma unroll
  for (int kk = 0; kk < 8; kk++) {
    const int k = kk * 32;
    bf8 Bv[4];
#pragma unroll
    for (int nt = 0; nt < 4; nt++) Bv[nt] = *(const bf8*)&h2T[nt * 16 + l15][k + l4 * 8];
#pragma unroll
    for (int mt = 0; mt < 4; mt++) {
      bf8 Av = *(const bf8*)(W2p + (size_t)(w * 64 + mt * 16 + l15) * 256 + k + l4 * 8);
#pragma unroll
      for (int nt = 0; nt < 4; nt++)
        acc[mt][nt] = __builtin_amdgcn_mfma_f32_16x16x32_bf16(Av, Bv[nt], acc[mt][nt], 0, 0, 0);
    }
  }
#pragma unroll
  for (int mt = 0; mt < 4; mt++) {
    int q = w * 64 + mt * 16 + l4 * 4;
#pragma unroll
    for (int nt = 0; nt < 4; nt++) {
      int t = t0 + nt * 16 + l15;
#pragma unroll
      for (int r = 0; r < 4; r++)
        out[((size_t)b * NQ + q + r) * TT + t] = acc[mt][nt][r] + b2[q + r];
    }
  }
}

extern "C" void kernel_launch(void* const* d_in, const int* in_sizes, int n_in,
                              void* d_out, int out_size, void* d_ws, size_t ws_size,
                              hipStream_t stream) {
  const float* wave  = (const float*)d_in[0];
  const float* W_in  = (const float*)d_in[1];
  const float* b_in  = (const float*)d_in[2];
  const float* Wf    = (const float*)d_in[3];
  const float* bf    = (const float*)d_in[4];
  const float* Wg    = (const float*)d_in[5];
  const float* bg    = (const float*)d_in[6];
  const float* Wres  = (const float*)d_in[7];
  const float* bres  = (const float*)d_in[8];
  const float* Wskip = (const float*)d_in[9];
  const float* bskip = (const float*)d_in[10];
  const float* W1    = (const float*)d_in[11];
  const float* b1    = (const float*)d_in[12];
  const float* W2    = (const float*)d_in[13];
  const float* b2    = (const float*)d_in[14];
  float* out = (float*)d_out;

  char* ws = (char*)d_ws;
  short* xA   = (short*)ws;                    // 33,554,432 B
  short* xB   = (short*)(ws + 33554432);       // 33,554,432 B
  short* Afg  = (short*)(ws + 67108864);       //  2,097,152 B
  short* Ars  = (short*)(ws + 69206016);       //  1,572,864 B
  short* W1p  = (short*)(ws + 70778880);       //    131,072 B
  short* W2p  = (short*)(ws + 70909952);       //    131,072 B
  float* biasp = (float*)(ws + 71041024);      //     40,960 B  (total ~71.1 MB)

  k_pack<<<1024, 256, 0, stream>>>(Wf, Wg, Wres, Wskip, W1, W2, bf, bg, bres, bskip,
                                   Afg, Ars, W1p, W2p, biasp);
  k_input<<<(NBATCH * TT) / 256, 256, 0, stream>>>(wave, W_in, b_in, xA);

  static const int dils[16] = {1, 2, 4, 8, 16, 32, 64, 128,
                               1, 2, 4, 8, 16, 32, 64, 128};
  const short* xi = xA;
  short* xo = xB;
  for (int i = 0; i < 16; i++) {
    k_res_mfma<<<dim3(TT / NT, NBATCH), 256, 0, stream>>>(
        xi, xo, out, Afg + (size_t)i * 65536, Ars + (size_t)i * 49152,
        biasp, i, dils[i], i == 0 ? 1 : 0);
    short* tmp = (short*)xi; xi = xo; xo = tmp;
  }
  k_head_mfma<<<dim3(TT / NT, NBATCH), 256, 0, stream>>>(out, W1p, b1, W2p, b2, out);
}